// Round 1
// baseline (267.058 us; speedup 1.0000x reference)
//
#include <hip/hip_runtime.h>
#include <hip/hip_bf16.h>

// ContrastiveLoss: N=8192, D=512 fp32 features, int labels {0,1}.
// out = mean_i [ (np_i * log(sum_exp_i) - sum_pos_i) / (np_i + 1e-8) ]
//   sum_exp_i = sum_{j!=i} exp(10 * f_i.f_j)   (f = L2-normalized rows)
//   sum_pos_i = sum_{j!=i, lab_j==lab_i} 10 * f_i.f_j
//   np_i      = count(lab == lab_i) - 1
// eps-inside-log dropped: perturbs result by ~1e-6 (threshold 0.18).
// Pipeline: normalize->bf16 | zero accum | count labels | tiled MFMA "gemm"
// with fused exp/mask epilogue + atomics | final reduce.

#define N_ROWS 8192
#define DIM 512
#define INV_T 10.0f

typedef __bf16 bf16_t;
typedef bf16_t bf16x8 __attribute__((ext_vector_type(8)));
typedef bf16_t bf16x4 __attribute__((ext_vector_type(4)));
typedef float f32x4 __attribute__((ext_vector_type(4)));

__global__ __launch_bounds__(256) void zero_kernel(float* __restrict__ p, int n) {
    int i = blockIdx.x * blockDim.x + threadIdx.x;
    if (i < n) p[i] = 0.0f;
}

// One wave per row: fp32 sum-of-squares, rsqrt scale, bf16 (RN) store.
__global__ __launch_bounds__(64) void norm_kernel(const float* __restrict__ x,
                                                  bf16_t* __restrict__ out) {
    const int row = blockIdx.x;
    const float4* xr = (const float4*)(x + (size_t)row * DIM);
    const int t = threadIdx.x;
    float4 v0 = xr[t];
    float4 v1 = xr[t + 64];
    float ss = v0.x * v0.x + v0.y * v0.y + v0.z * v0.z + v0.w * v0.w +
               v1.x * v1.x + v1.y * v1.y + v1.z * v1.z + v1.w * v1.w;
#pragma unroll
    for (int off = 32; off >= 1; off >>= 1) ss += __shfl_xor(ss, off, 64);
    float inv = 1.0f / fmaxf(sqrtf(ss), 1e-12f);
    bf16x4 o0 = {(bf16_t)(v0.x * inv), (bf16_t)(v0.y * inv),
                 (bf16_t)(v0.z * inv), (bf16_t)(v0.w * inv)};
    bf16x4 o1 = {(bf16_t)(v1.x * inv), (bf16_t)(v1.y * inv),
                 (bf16_t)(v1.z * inv), (bf16_t)(v1.w * inv)};
    *(bf16x4*)(out + (size_t)row * DIM + 4 * t) = o0;
    *(bf16x4*)(out + (size_t)row * DIM + 4 * (t + 64)) = o1;
}

__global__ __launch_bounds__(256) void count_kernel(const int* __restrict__ lab,
                                                    int* __restrict__ cnt) {
    int local = 0;
    for (int i = threadIdx.x; i < N_ROWS; i += 256) local += lab[i];  // labels in {0,1}
    __shared__ int sh[4];
    int lane = threadIdx.x & 63, w = threadIdx.x >> 6;
#pragma unroll
    for (int off = 32; off >= 1; off >>= 1) local += __shfl_xor(local, off, 64);
    if (lane == 0) sh[w] = local;
    __syncthreads();
    if (threadIdx.x == 0) {
        int c1 = sh[0] + sh[1] + sh[2] + sh[3];
        cnt[0] = N_ROWS - c1;
        cnt[1] = c1;
    }
}

// 128x128 sim tile per block (4 waves, 2x2; each wave 64x64 via 4x4 MFMA
// 16x16x32 bf16). BK=64 staged in LDS. Fused epilogue: exp + label mask,
// 16-lane shuffle reduce along cols, atomicAdd per-row partials.
__global__ __launch_bounds__(256, 2) void sim_kernel(const bf16_t* __restrict__ fbf,
                                                     const int* __restrict__ lab,
                                                     float* __restrict__ sum_exp,
                                                     float* __restrict__ sum_pos) {
    __shared__ bf16_t sA[128][64];
    __shared__ bf16_t sB[128][64];
    const int t = threadIdx.x;
    const int blk = blockIdx.x;
    const int bi = blk >> 6, bj = blk & 63;
    const int iBase = bi * 128, jBase = bj * 128;
    const int lane = t & 63, wave = t >> 6;
    const int wm = wave >> 1, wn = wave & 1;
    const int lrow = lane & 15, quad = lane >> 4;

    f32x4 acc[4][4] = {};

    for (int kk = 0; kk < DIM; kk += 64) {
#pragma unroll
        for (int it = 0; it < 4; ++it) {
            int L = it * 256 + t;
            int r = L >> 3;
            int c = (L & 7) * 8;
            *(uint4*)(&sA[r][c]) = *(const uint4*)(fbf + (size_t)(iBase + r) * DIM + kk + c);
            *(uint4*)(&sB[r][c]) = *(const uint4*)(fbf + (size_t)(jBase + r) * DIM + kk + c);
        }
        __syncthreads();
#pragma unroll
        for (int ks = 0; ks < 64; ks += 32) {
            bf16x8 af[4], bfr[4];
#pragma unroll
            for (int m = 0; m < 4; ++m)
                af[m] = *(const bf16x8*)(&sA[wm * 64 + m * 16 + lrow][ks + quad * 8]);
#pragma unroll
            for (int n = 0; n < 4; ++n)
                bfr[n] = *(const bf16x8*)(&sB[wn * 64 + n * 16 + lrow][ks + quad * 8]);
#pragma unroll
            for (int m = 0; m < 4; ++m) {
#pragma unroll
                for (int n = 0; n < 4; ++n) {
                    acc[m][n] = __builtin_amdgcn_mfma_f32_16x16x32_bf16(
                        af[m], bfr[n], acc[m][n], 0, 0, 0);
                }
            }
        }
        __syncthreads();
    }

    // Epilogue. C/D layout (m89-verified): col = lane&15, row = quad*4 + reg.
    int labj[4];
#pragma unroll
    for (int n = 0; n < 4; ++n) labj[n] = lab[jBase + wn * 64 + n * 16 + lrow];
#pragma unroll
    for (int m = 0; m < 4; ++m) {
#pragma unroll
        for (int e = 0; e < 4; ++e) {
            int i = iBase + wm * 64 + m * 16 + quad * 4 + e;
            int labi = lab[i];
            float se = 0.0f, sp = 0.0f;
#pragma unroll
            for (int n = 0; n < 4; ++n) {
                int j = jBase + wn * 64 + n * 16 + lrow;
                float sim = acc[m][n][e] * INV_T;
                if (j != i) {
                    se += __expf(sim);
                    if (labj[n] == labi) sp += sim;
                }
            }
#pragma unroll
            for (int off = 8; off >= 1; off >>= 1) {
                se += __shfl_xor(se, off, 16);
                sp += __shfl_xor(sp, off, 16);
            }
            if (lrow == 0) {
                atomicAdd(&sum_exp[i], se);
                atomicAdd(&sum_pos[i], sp);
            }
        }
    }
}

__global__ __launch_bounds__(256) void final_kernel(const float* __restrict__ sum_exp,
                                                    const float* __restrict__ sum_pos,
                                                    const int* __restrict__ lab,
                                                    const int* __restrict__ cnt,
                                                    float* __restrict__ out) {
    float local = 0.0f;
    for (int i = threadIdx.x; i < N_ROWS; i += 256) {
        float np = (float)(cnt[lab[i]] - 1);
        float pr = (np * logf(sum_exp[i]) - sum_pos[i]) / (np + 1e-8f);
        local += pr;
    }
    __shared__ float sh[4];
    int lane = threadIdx.x & 63, w = threadIdx.x >> 6;
#pragma unroll
    for (int off = 32; off >= 1; off >>= 1) local += __shfl_xor(local, off, 64);
    if (lane == 0) sh[w] = local;
    __syncthreads();
    if (threadIdx.x == 0)
        out[0] = (sh[0] + sh[1] + sh[2] + sh[3]) / (float)N_ROWS;
}

extern "C" void kernel_launch(void* const* d_in, const int* in_sizes, int n_in,
                              void* d_out, int out_size, void* d_ws, size_t ws_size,
                              hipStream_t stream) {
    const float* features = (const float*)d_in[0];
    const int* labels = (const int*)d_in[1];
    float* out = (float*)d_out;

    char* ws = (char*)d_ws;
    bf16_t* fbf = (bf16_t*)ws;                                   // 8 MiB
    float* sum_exp = (float*)(ws + (size_t)N_ROWS * DIM * 2);    // 32 KiB
    float* sum_pos = sum_exp + N_ROWS;                           // 32 KiB
    int* cnt = (int*)(sum_pos + N_ROWS);                         // 8 B

    zero_kernel<<<(2 * N_ROWS + 255) / 256, 256, 0, stream>>>(sum_exp, 2 * N_ROWS);
    norm_kernel<<<N_ROWS, 64, 0, stream>>>(features, fbf);
    count_kernel<<<1, 256, 0, stream>>>(labels, cnt);
    sim_kernel<<<4096, 256, 0, stream>>>(fbf, labels, sum_exp, sum_pos);
    final_kernel<<<1, 256, 0, stream>>>(sum_exp, sum_pos, labels, cnt, out);
}

// Round 2
// 234.917 us; speedup vs baseline: 1.1368x; 1.1368x over previous
//
#include <hip/hip_runtime.h>
#include <hip/hip_bf16.h>

// ContrastiveLoss: N=8192, D=512 fp32 features, int labels {0,1}.
// out = mean_i [ (np_i * log(sum_exp_i) - sum_pos_i) / (np_i + 1e-8) ]
//   sum_exp_i = sum_{j!=i} exp(10 * f_i.f_j)   (f = L2-normalized rows)
//   sum_pos_i = sum_{j!=i, lab_j==lab_i} 10 * f_i.f_j
//   np_i      = count(lab == lab_i) - 1
// R1: +global_load_lds width-16 staging with XOR-swizzled LDS layout
//     (phys 16B-unit = logical ^ (row&7)) -> async DMA staging AND
//     conflict-free ds_read_b128 (row stride 128B = 32 banks was a 2x
//     read conflict in R0: SQ_LDS_BANK_CONFLICT 2.5e7).

#define N_ROWS 8192
#define DIM 512
#define INV_T 10.0f
#define BK 64

typedef __bf16 bf16_t;
typedef bf16_t bf16x8 __attribute__((ext_vector_type(8)));
typedef bf16_t bf16x4 __attribute__((ext_vector_type(4)));
typedef float f32x4 __attribute__((ext_vector_type(4)));

__device__ static inline void gload_lds16(const bf16_t* g, bf16_t* l) {
    __builtin_amdgcn_global_load_lds(
        (const __attribute__((address_space(1))) unsigned int*)g,
        (__attribute__((address_space(3))) unsigned int*)l, 16, 0, 0);
}

__global__ __launch_bounds__(256) void zero_kernel(float* __restrict__ p, int n) {
    int i = blockIdx.x * blockDim.x + threadIdx.x;
    if (i < n) p[i] = 0.0f;
}

// 256 threads = 4 waves, one row per wave. fp32 sumsq, rsqrt, bf16 store.
__global__ __launch_bounds__(256) void norm_kernel(const float* __restrict__ x,
                                                   bf16_t* __restrict__ out) {
    const int wave = threadIdx.x >> 6, t = threadIdx.x & 63;
    const int row = blockIdx.x * 4 + wave;
    const float4* xr = (const float4*)(x + (size_t)row * DIM);
    float4 v0 = xr[t];
    float4 v1 = xr[t + 64];
    float ss = v0.x * v0.x + v0.y * v0.y + v0.z * v0.z + v0.w * v0.w +
               v1.x * v1.x + v1.y * v1.y + v1.z * v1.z + v1.w * v1.w;
#pragma unroll
    for (int off = 32; off >= 1; off >>= 1) ss += __shfl_xor(ss, off, 64);
    float inv = 1.0f / fmaxf(sqrtf(ss), 1e-12f);
    bf16x4 o0 = {(bf16_t)(v0.x * inv), (bf16_t)(v0.y * inv),
                 (bf16_t)(v0.z * inv), (bf16_t)(v0.w * inv)};
    bf16x4 o1 = {(bf16_t)(v1.x * inv), (bf16_t)(v1.y * inv),
                 (bf16_t)(v1.z * inv), (bf16_t)(v1.w * inv)};
    *(bf16x4*)(out + (size_t)row * DIM + 4 * t) = o0;
    *(bf16x4*)(out + (size_t)row * DIM + 4 * (t + 64)) = o1;
}

__global__ __launch_bounds__(256) void count_kernel(const int* __restrict__ lab,
                                                    int* __restrict__ cnt) {
    int local = 0;
    for (int i = threadIdx.x; i < N_ROWS; i += 256) local += lab[i];  // labels in {0,1}
    __shared__ int sh[4];
    int lane = threadIdx.x & 63, w = threadIdx.x >> 6;
#pragma unroll
    for (int off = 32; off >= 1; off >>= 1) local += __shfl_xor(local, off, 64);
    if (lane == 0) sh[w] = local;
    __syncthreads();
    if (threadIdx.x == 0) {
        int c1 = sh[0] + sh[1] + sh[2] + sh[3];
        cnt[0] = N_ROWS - c1;
        cnt[1] = c1;
    }
}

// 128x128 sim tile per block (4 waves 2x2, each 64x64 via 4x4 MFMA 16x16x32).
// BK=64 via global_load_lds(16B) into XOR-swizzled LDS:
//   LDS offset of (row, logical 16B-unit u) = row*128B + (u ^ (row&7))*16B.
// Staging: lane L of a wave-instr writes phys slot L of an 8-row chunk; its
// global source col-unit is (L&7) ^ ((L>>3)&7) -- a permutation within each
// contiguous 128B row chunk, so coalescing is preserved.
// Reads: start bank = 4*((u^ (lrow&7))) -> 8 lanes per 4-bank group = minimal.
__global__ __launch_bounds__(256, 4) void sim_kernel(const bf16_t* __restrict__ fbf,
                                                     const int* __restrict__ lab,
                                                     float* __restrict__ sum_exp,
                                                     float* __restrict__ sum_pos) {
    __shared__ bf16_t sA[128 * 64];
    __shared__ bf16_t sB[128 * 64];
    const int t = threadIdx.x;
    const int bi = blockIdx.x >> 6, bj = blockIdx.x & 63;
    const int iBase = bi * 128, jBase = bj * 128;
    const int lane = t & 63, wave = t >> 6;
    const int wm = wave >> 1, wn = wave & 1;
    const int lrow = lane & 15, quad = lane >> 4;

    // staging decomposition: lane -> (row-in-chunk, logical col unit)
    const int sub = lane >> 3;        // 0..7
    const int lu = (lane & 7) ^ sub;  // logical 16B unit, swizzled
    const size_t gOffA = (size_t)(iBase + sub) * DIM + lu * 8;
    const size_t gOffB = (size_t)(jBase + sub) * DIM + lu * 8;

    f32x4 acc[4][4] = {};

    for (int kk = 0; kk < DIM; kk += BK) {
#pragma unroll
        for (int c = 0; c < 4; ++c) {
            const int rowc = wave * 32 + c * 8;  // chunk base row (mult of 8)
            gload_lds16(fbf + gOffA + (size_t)rowc * DIM + kk, &sA[rowc * 64]);
            gload_lds16(fbf + gOffB + (size_t)rowc * DIM + kk, &sB[rowc * 64]);
        }
        __syncthreads();
#pragma unroll
        for (int ks = 0; ks < BK; ks += 32) {
            const int su = (((ks >> 3) + quad) ^ (lrow & 7)) * 8;  // swizzled byte/2 off
            bf16x8 af[4], bfr[4];
#pragma unroll
            for (int m = 0; m < 4; ++m)
                af[m] = *(const bf16x8*)(&sA[(wm * 64 + m * 16 + lrow) * 64 + su]);
#pragma unroll
            for (int n = 0; n < 4; ++n)
                bfr[n] = *(const bf16x8*)(&sB[(wn * 64 + n * 16 + lrow) * 64 + su]);
#pragma unroll
            for (int m = 0; m < 4; ++m) {
#pragma unroll
                for (int n = 0; n < 4; ++n) {
                    acc[m][n] = __builtin_amdgcn_mfma_f32_16x16x32_bf16(
                        af[m], bfr[n], acc[m][n], 0, 0, 0);
                }
            }
        }
        __syncthreads();
    }

    // Epilogue. C/D layout (m89-verified): col = lane&15, row = quad*4 + reg.
    int labj[4];
#pragma unroll
    for (int n = 0; n < 4; ++n) labj[n] = lab[jBase + wn * 64 + n * 16 + lrow];
#pragma unroll
    for (int m = 0; m < 4; ++m) {
#pragma unroll
        for (int e = 0; e < 4; ++e) {
            int i = iBase + wm * 64 + m * 16 + quad * 4 + e;
            int labi = lab[i];
            float se = 0.0f, sp = 0.0f;
#pragma unroll
            for (int n = 0; n < 4; ++n) {
                int j = jBase + wn * 64 + n * 16 + lrow;
                float sim = acc[m][n][e] * INV_T;
                if (j != i) {
                    se += __expf(sim);
                    if (labj[n] == labi) sp += sim;
                }
            }
#pragma unroll
            for (int off = 8; off >= 1; off >>= 1) {
                se += __shfl_xor(se, off, 16);
                sp += __shfl_xor(sp, off, 16);
            }
            if (lrow == 0) {
                atomicAdd(&sum_exp[i], se);
                atomicAdd(&sum_pos[i], sp);
            }
        }
    }
}

__global__ __launch_bounds__(256) void final_kernel(const float* __restrict__ sum_exp,
                                                    const float* __restrict__ sum_pos,
                                                    const int* __restrict__ lab,
                                                    const int* __restrict__ cnt,
                                                    float* __restrict__ out) {
    float local = 0.0f;
    for (int i = threadIdx.x; i < N_ROWS; i += 256) {
        float np = (float)(cnt[lab[i]] - 1);
        float pr = (np * logf(sum_exp[i]) - sum_pos[i]) / (np + 1e-8f);
        local += pr;
    }
    __shared__ float sh[4];
    int lane = threadIdx.x & 63, w = threadIdx.x >> 6;
#pragma unroll
    for (int off = 32; off >= 1; off >>= 1) local += __shfl_xor(local, off, 64);
    if (lane == 0) sh[w] = local;
    __syncthreads();
    if (threadIdx.x == 0)
        out[0] = (sh[0] + sh[1] + sh[2] + sh[3]) / (float)N_ROWS;
}

extern "C" void kernel_launch(void* const* d_in, const int* in_sizes, int n_in,
                              void* d_out, int out_size, void* d_ws, size_t ws_size,
                              hipStream_t stream) {
    const float* features = (const float*)d_in[0];
    const int* labels = (const int*)d_in[1];
    float* out = (float*)d_out;

    char* ws = (char*)d_ws;
    bf16_t* fbf = (bf16_t*)ws;                                   // 8 MiB
    float* sum_exp = (float*)(ws + (size_t)N_ROWS * DIM * 2);    // 32 KiB
    float* sum_pos = sum_exp + N_ROWS;                           // 32 KiB
    int* cnt = (int*)(sum_pos + N_ROWS);                         // 8 B

    zero_kernel<<<(2 * N_ROWS + 255) / 256, 256, 0, stream>>>(sum_exp, 2 * N_ROWS);
    norm_kernel<<<N_ROWS / 4, 256, 0, stream>>>(features, fbf);
    count_kernel<<<1, 256, 0, stream>>>(labels, cnt);
    sim_kernel<<<4096, 256, 0, stream>>>(fbf, labels, sum_exp, sum_pos);
    final_kernel<<<1, 256, 0, stream>>>(sum_exp, sum_pos, labels, cnt, out);
}

// Round 3
// 180.397 us; speedup vs baseline: 1.4804x; 1.3022x over previous
//
#include <hip/hip_runtime.h>
#include <hip/hip_bf16.h>

// ContrastiveLoss: N=8192, D=512 fp32 features, int labels {0,1}.
// out = mean_i [ (np_i * log(sum_exp_i) - sum_pos_i) / (np_i + 1e-8) ]
// R1: global_load_lds(16B) + XOR-swizzled LDS -> bank conflicts 2.5e7 -> 0.
// R2: symmetry: only upper-triangle tiles (2080 of 4096); off-diag tiles
//     scatter both row-sums (over cols) and col-sums (over rows, reusing the
//     same exp). Parallelized count/final (were single-block serial tails).

#define N_ROWS 8192
#define DIM 512
#define INV_T 10.0f
#define BK 64
#define NB 64  // 8192/128 tile grid dim

typedef __bf16 bf16_t;
typedef bf16_t bf16x8 __attribute__((ext_vector_type(8)));
typedef bf16_t bf16x4 __attribute__((ext_vector_type(4)));
typedef float f32x4 __attribute__((ext_vector_type(4)));

__device__ static inline void gload_lds16(const bf16_t* g, bf16_t* l) {
    __builtin_amdgcn_global_load_lds(
        (const __attribute__((address_space(1))) unsigned int*)g,
        (__attribute__((address_space(3))) unsigned int*)l, 16, 0, 0);
}

// Zero sum_exp/sum_pos (16384 floats) + cnt + out. 64 blocks.
__global__ __launch_bounds__(256) void zero_kernel(float* __restrict__ acc,
                                                   int* __restrict__ cnt,
                                                   float* __restrict__ out) {
    int i = blockIdx.x * blockDim.x + threadIdx.x;
    acc[i] = 0.0f;
    if (i == 0) { cnt[0] = 0; out[0] = 0.0f; }
}

// 4 waves/block, one row per wave. fp32 sumsq, rsqrt, bf16 store.
__global__ __launch_bounds__(256) void norm_kernel(const float* __restrict__ x,
                                                   bf16_t* __restrict__ out) {
    const int wave = threadIdx.x >> 6, t = threadIdx.x & 63;
    const int row = blockIdx.x * 4 + wave;
    const float4* xr = (const float4*)(x + (size_t)row * DIM);
    float4 v0 = xr[t];
    float4 v1 = xr[t + 64];
    float ss = v0.x * v0.x + v0.y * v0.y + v0.z * v0.z + v0.w * v0.w +
               v1.x * v1.x + v1.y * v1.y + v1.z * v1.z + v1.w * v1.w;
#pragma unroll
    for (int off = 32; off >= 1; off >>= 1) ss += __shfl_xor(ss, off, 64);
    float inv = 1.0f / fmaxf(sqrtf(ss), 1e-12f);
    bf16x4 o0 = {(bf16_t)(v0.x * inv), (bf16_t)(v0.y * inv),
                 (bf16_t)(v0.z * inv), (bf16_t)(v0.w * inv)};
    bf16x4 o1 = {(bf16_t)(v1.x * inv), (bf16_t)(v1.y * inv),
                 (bf16_t)(v1.z * inv), (bf16_t)(v1.w * inv)};
    *(bf16x4*)(out + (size_t)row * DIM + 4 * t) = o0;
    *(bf16x4*)(out + (size_t)row * DIM + 4 * (t + 64)) = o1;
}

// 16 blocks: per-block label-1 count -> atomicAdd cnt[0].
__global__ __launch_bounds__(256) void count_kernel(const int* __restrict__ lab,
                                                    int* __restrict__ cnt) {
    int local = lab[blockIdx.x * 512 + threadIdx.x] +
                lab[blockIdx.x * 512 + 256 + threadIdx.x];
    __shared__ int sh[4];
    int lane = threadIdx.x & 63, w = threadIdx.x >> 6;
#pragma unroll
    for (int off = 32; off >= 1; off >>= 1) local += __shfl_xor(local, off, 64);
    if (lane == 0) sh[w] = local;
    __syncthreads();
    if (threadIdx.x == 0) atomicAdd(cnt, sh[0] + sh[1] + sh[2] + sh[3]);
}

// 128x128 tile per block (4 waves 2x2, each 64x64 via 4x4 MFMA 16x16x32 bf16).
// Upper-triangle tiles only. BK=64 via global_load_lds into XOR-swizzled LDS
// (phys 16B-unit = logical ^ (row&7)): async DMA + conflict-free b128 reads.
__global__ __launch_bounds__(256, 4) void sim_kernel(const bf16_t* __restrict__ fbf,
                                                     const int* __restrict__ lab,
                                                     float* __restrict__ sum_exp,
                                                     float* __restrict__ sum_pos) {
    __shared__ bf16_t sA[128 * 64];
    __shared__ bf16_t sB[128 * 64];
    // decode upper-triangle index: S(b) = b*(129-b)/2
    const int tblk = blockIdx.x;
    int bi = (int)(64.5f - sqrtf(64.5f * 64.5f - 2.0f * (float)tblk));
    while (bi * (129 - bi) / 2 > tblk) --bi;
    while ((bi + 1) * (128 - bi) / 2 <= tblk) ++bi;
    const int bj = bi + (tblk - bi * (129 - bi) / 2);
    const bool diag = (bi == bj);

    const int t = threadIdx.x;
    const int iBase = bi * 128, jBase = bj * 128;
    const int lane = t & 63, wave = t >> 6;
    const int wm = wave >> 1, wn = wave & 1;
    const int lrow = lane & 15, quad = lane >> 4;

    const int sub = lane >> 3;        // row within 8-row staging chunk
    const int lu = (lane & 7) ^ sub;  // swizzled 16B col unit
    const size_t gOffA = (size_t)(iBase + sub) * DIM + lu * 8;
    const size_t gOffB = (size_t)(jBase + sub) * DIM + lu * 8;

    f32x4 acc[4][4] = {};

    for (int kk = 0; kk < DIM; kk += BK) {
#pragma unroll
        for (int c = 0; c < 4; ++c) {
            const int rowc = wave * 32 + c * 8;
            gload_lds16(fbf + gOffA + (size_t)rowc * DIM + kk, &sA[rowc * 64]);
            gload_lds16(fbf + gOffB + (size_t)rowc * DIM + kk, &sB[rowc * 64]);
        }
        __syncthreads();
#pragma unroll
        for (int ks = 0; ks < BK; ks += 32) {
            const int su = (((ks >> 3) + quad) ^ (lrow & 7)) * 8;
            bf16x8 af[4], bfr[4];
#pragma unroll
            for (int m = 0; m < 4; ++m)
                af[m] = *(const bf16x8*)(&sA[(wm * 64 + m * 16 + lrow) * 64 + su]);
#pragma unroll
            for (int n = 0; n < 4; ++n)
                bfr[n] = *(const bf16x8*)(&sB[(wn * 64 + n * 16 + lrow) * 64 + su]);
#pragma unroll
            for (int m = 0; m < 4; ++m)
#pragma unroll
                for (int n = 0; n < 4; ++n)
                    acc[m][n] = __builtin_amdgcn_mfma_f32_16x16x32_bf16(
                        af[m], bfr[n], acc[m][n], 0, 0, 0);
        }
        __syncthreads();
    }

    // Epilogue. C/D layout: col = lane&15, row = quad*4 + reg (m89-verified).
    int labj[4];
#pragma unroll
    for (int n = 0; n < 4; ++n) labj[n] = lab[jBase + wn * 64 + n * 16 + lrow];

    if (diag) {
        // row-sums only; exclude j == i
#pragma unroll
        for (int m = 0; m < 4; ++m) {
#pragma unroll
            for (int e = 0; e < 4; ++e) {
                int i = iBase + wm * 64 + m * 16 + quad * 4 + e;
                int labi = lab[i];
                float se = 0.0f, sp = 0.0f;
#pragma unroll
                for (int n = 0; n < 4; ++n) {
                    int j = jBase + wn * 64 + n * 16 + lrow;
                    float sim = acc[m][n][e] * INV_T;
                    if (j != i) {
                        se += __expf(sim);
                        if (labj[n] == labi) sp += sim;
                    }
                }
#pragma unroll
                for (int off = 8; off >= 1; off >>= 1) {
                    se += __shfl_xor(se, off, 16);
                    sp += __shfl_xor(sp, off, 16);
                }
                if (lrow == 0) {
                    atomicAdd(&sum_exp[i], se);
                    atomicAdd(&sum_pos[i], sp);
                }
            }
        }
    } else {
        // off-diagonal: i != j guaranteed; scatter rows (i) AND cols (j)
        float sec[4] = {0, 0, 0, 0}, spc[4] = {0, 0, 0, 0};
#pragma unroll
        for (int m = 0; m < 4; ++m) {
#pragma unroll
            for (int e = 0; e < 4; ++e) {
                int i = iBase + wm * 64 + m * 16 + quad * 4 + e;
                int labi = lab[i];
                float se = 0.0f, sp = 0.0f;
#pragma unroll
                for (int n = 0; n < 4; ++n) {
                    float sim = acc[m][n][e] * INV_T;
                    float ex = __expf(sim);
                    se += ex;
                    sec[n] += ex;
                    if (labj[n] == labi) {
                        sp += sim;
                        spc[n] += sim;
                    }
                }
#pragma unroll
                for (int off = 8; off >= 1; off >>= 1) {
                    se += __shfl_xor(se, off, 16);
                    sp += __shfl_xor(sp, off, 16);
                }
                if (lrow == 0) {
                    atomicAdd(&sum_exp[i], se);
                    atomicAdd(&sum_pos[i], sp);
                }
            }
        }
        // col reduce: in-lane covered m,e (16 rows of our quad); fold quads
#pragma unroll
        for (int n = 0; n < 4; ++n) {
            sec[n] += __shfl_xor(sec[n], 16, 64);
            sec[n] += __shfl_xor(sec[n], 32, 64);
            spc[n] += __shfl_xor(spc[n], 16, 64);
            spc[n] += __shfl_xor(spc[n], 32, 64);
        }
        if (quad == 0) {
#pragma unroll
            for (int n = 0; n < 4; ++n) {
                int j = jBase + wn * 64 + n * 16 + lrow;
                atomicAdd(&sum_exp[j], sec[n]);
                atomicAdd(&sum_pos[j], spc[n]);
            }
        }
    }
}

// 32 blocks x 256 rows: per-row loss, block-reduce, atomicAdd mean into out.
__global__ __launch_bounds__(256) void final_kernel(const float* __restrict__ sum_exp,
                                                    const float* __restrict__ sum_pos,
                                                    const int* __restrict__ lab,
                                                    const int* __restrict__ cnt,
                                                    float* __restrict__ out) {
    const int i = blockIdx.x * 256 + threadIdx.x;
    const float c1 = (float)cnt[0];
    float np = (lab[i] ? c1 : (float)N_ROWS - c1) - 1.0f;
    float local = (np * __logf(sum_exp[i]) - sum_pos[i]) / (np + 1e-8f);
    __shared__ float sh[4];
    int lane = threadIdx.x & 63, w = threadIdx.x >> 6;
#pragma unroll
    for (int off = 32; off >= 1; off >>= 1) local += __shfl_xor(local, off, 64);
    if (lane == 0) sh[w] = local;
    __syncthreads();
    if (threadIdx.x == 0)
        atomicAdd(out, (sh[0] + sh[1] + sh[2] + sh[3]) * (1.0f / (float)N_ROWS));
}

extern "C" void kernel_launch(void* const* d_in, const int* in_sizes, int n_in,
                              void* d_out, int out_size, void* d_ws, size_t ws_size,
                              hipStream_t stream) {
    const float* features = (const float*)d_in[0];
    const int* labels = (const int*)d_in[1];
    float* out = (float*)d_out;

    char* ws = (char*)d_ws;
    bf16_t* fbf = (bf16_t*)ws;                                   // 8 MiB
    float* sum_exp = (float*)(ws + (size_t)N_ROWS * DIM * 2);    // 32 KiB
    float* sum_pos = sum_exp + N_ROWS;                           // 32 KiB
    int* cnt = (int*)(sum_pos + N_ROWS);                         // 4 B

    zero_kernel<<<64, 256, 0, stream>>>(sum_exp, cnt, out);
    norm_kernel<<<N_ROWS / 4, 256, 0, stream>>>(features, fbf);
    count_kernel<<<16, 256, 0, stream>>>(labels, cnt);
    sim_kernel<<<NB * (NB + 1) / 2, 256, 0, stream>>>(fbf, labels, sum_exp, sum_pos);
    final_kernel<<<32, 256, 0, stream>>>(sum_exp, sum_pos, labels, cnt, out);
}

// Round 4
// 180.308 us; speedup vs baseline: 1.4811x; 1.0005x over previous
//
#include <hip/hip_runtime.h>
#include <hip/hip_bf16.h>

// ContrastiveLoss: N=8192, D=512 fp32 features, int labels {0,1}.
// out = mean_i [ (np_i * log(sum_exp_i) - sum_pos_i) / (np_i + 1e-8) ]
// R1: global_load_lds(16B) + XOR-swizzled LDS -> bank conflicts 2.5e7 -> 0.
// R2: upper-triangle tiles only; off-diag scatters row+col sums.
// R3: device atomics (2.1M, ~190MB L2-miss RMW fabric traffic) replaced by a
//     collision-free partial-sum buffer: block (bi,bj) stores row-partials to
//     slot bj, col-partials to slot bi (diag skips cols) -> each (slot,row)
//     written exactly once, plain stores. Wave-pair dupes folded via 2KB LDS
//     float atomics. 5 launches -> 3 (count/zero folded into norm).

#define N_ROWS 8192
#define DIM 512
#define INV_T 10.0f
#define BK 64
#define NB 64     // 8192/128 tile grid
#define NSLOT 64  // partial-sum slots

typedef __bf16 bf16_t;
typedef bf16_t bf16x8 __attribute__((ext_vector_type(8)));
typedef bf16_t bf16x4 __attribute__((ext_vector_type(4)));
typedef float f32x4 __attribute__((ext_vector_type(4)));

__device__ static inline void gload_lds16(const bf16_t* g, bf16_t* l) {
    __builtin_amdgcn_global_load_lds(
        (const __attribute__((address_space(1))) unsigned int*)g,
        (__attribute__((address_space(3))) unsigned int*)l, 16, 0, 0);
}

// 4 waves/block, one row per wave: fp32 sumsq -> rsqrt -> bf16 store.
// Block 0 additionally: count label-1s (whole array) + zero out[0].
__global__ __launch_bounds__(256) void norm_kernel(const float* __restrict__ x,
                                                   bf16_t* __restrict__ outb,
                                                   const int* __restrict__ lab,
                                                   int* __restrict__ cnt,
                                                   float* __restrict__ out) {
    __shared__ int shc[4];
    const int wave = threadIdx.x >> 6, t = threadIdx.x & 63;
    const int row = blockIdx.x * 4 + wave;
    const float4* xr = (const float4*)(x + (size_t)row * DIM);
    float4 v0 = xr[t];
    float4 v1 = xr[t + 64];
    float ss = v0.x * v0.x + v0.y * v0.y + v0.z * v0.z + v0.w * v0.w +
               v1.x * v1.x + v1.y * v1.y + v1.z * v1.z + v1.w * v1.w;
#pragma unroll
    for (int off = 32; off >= 1; off >>= 1) ss += __shfl_xor(ss, off, 64);
    float inv = 1.0f / fmaxf(sqrtf(ss), 1e-12f);
    bf16x4 o0 = {(bf16_t)(v0.x * inv), (bf16_t)(v0.y * inv),
                 (bf16_t)(v0.z * inv), (bf16_t)(v0.w * inv)};
    bf16x4 o1 = {(bf16_t)(v1.x * inv), (bf16_t)(v1.y * inv),
                 (bf16_t)(v1.z * inv), (bf16_t)(v1.w * inv)};
    *(bf16x4*)(outb + (size_t)row * DIM + 4 * t) = o0;
    *(bf16x4*)(outb + (size_t)row * DIM + 4 * (t + 64)) = o1;

    if (blockIdx.x == 0) {
        int local = 0;
        for (int i = threadIdx.x; i < N_ROWS; i += 256) local += lab[i];
#pragma unroll
        for (int off = 32; off >= 1; off >>= 1) local += __shfl_xor(local, off, 64);
        if (t == 0) shc[wave] = local;
        __syncthreads();
        if (threadIdx.x == 0) {
            cnt[0] = shc[0] + shc[1] + shc[2] + shc[3];
            out[0] = 0.0f;
        }
    }
}

// 128x128 tile per block (4 waves 2x2, each 64x64 via 4x4 MFMA 16x16x32 bf16).
// Upper-triangle tiles. global_load_lds(16B) into XOR-swizzled LDS
// (phys 16B-unit = logical ^ (row&7)): async DMA + conflict-free b128 reads.
// Epilogue: LDS-folded row/col partials -> plain stores into PE/PP slots.
__global__ __launch_bounds__(256, 4) void sim_kernel(const bf16_t* __restrict__ fbf,
                                                     const int* __restrict__ lab,
                                                     float* __restrict__ PE,
                                                     float* __restrict__ PP) {
    __shared__ bf16_t sA[128 * 64];
    __shared__ bf16_t sB[128 * 64];
    __shared__ float ldsF[512];  // [0,128)=rowE [128,256)=rowP [256,384)=colE [384,512)=colP

    const int tblk = blockIdx.x;
    int bi = (int)(64.5f - sqrtf(64.5f * 64.5f - 2.0f * (float)tblk));
    while (bi * (129 - bi) / 2 > tblk) --bi;
    while ((bi + 1) * (128 - bi) / 2 <= tblk) ++bi;
    const int bj = bi + (tblk - bi * (129 - bi) / 2);
    const bool diag = (bi == bj);

    const int t = threadIdx.x;
    const int iBase = bi * 128, jBase = bj * 128;
    const int lane = t & 63, wave = t >> 6;
    const int wm = wave >> 1, wn = wave & 1;
    const int lrow = lane & 15, quad = lane >> 4;

    const int sub = lane >> 3;        // row within 8-row staging chunk
    const int lu = (lane & 7) ^ sub;  // swizzled 16B col unit
    const size_t gOffA = (size_t)(iBase + sub) * DIM + lu * 8;
    const size_t gOffB = (size_t)(jBase + sub) * DIM + lu * 8;

    ldsF[t] = 0.0f;
    ldsF[t + 256] = 0.0f;

    f32x4 acc[4][4] = {};

    for (int kk = 0; kk < DIM; kk += BK) {
#pragma unroll
        for (int c = 0; c < 4; ++c) {
            const int rowc = wave * 32 + c * 8;
            gload_lds16(fbf + gOffA + (size_t)rowc * DIM + kk, &sA[rowc * 64]);
            gload_lds16(fbf + gOffB + (size_t)rowc * DIM + kk, &sB[rowc * 64]);
        }
        __syncthreads();
#pragma unroll
        for (int ks = 0; ks < BK; ks += 32) {
            const int su = (((ks >> 3) + quad) ^ (lrow & 7)) * 8;
            bf16x8 af[4], bfr[4];
#pragma unroll
            for (int m = 0; m < 4; ++m)
                af[m] = *(const bf16x8*)(&sA[(wm * 64 + m * 16 + lrow) * 64 + su]);
#pragma unroll
            for (int n = 0; n < 4; ++n)
                bfr[n] = *(const bf16x8*)(&sB[(wn * 64 + n * 16 + lrow) * 64 + su]);
#pragma unroll
            for (int m = 0; m < 4; ++m)
#pragma unroll
                for (int n = 0; n < 4; ++n)
                    acc[m][n] = __builtin_amdgcn_mfma_f32_16x16x32_bf16(
                        af[m], bfr[n], acc[m][n], 0, 0, 0);
        }
        __syncthreads();
    }
    // ldsF zero-writes are ordered before any ds_add by the barriers above.

    // Epilogue. C/D layout: col = lane&15, row = quad*4 + reg (m89-verified).
    int labj[4];
#pragma unroll
    for (int n = 0; n < 4; ++n) labj[n] = lab[jBase + wn * 64 + n * 16 + lrow];

    if (diag) {
#pragma unroll
        for (int m = 0; m < 4; ++m) {
#pragma unroll
            for (int e = 0; e < 4; ++e) {
                int r = wm * 64 + m * 16 + quad * 4 + e;
                int i = iBase + r;
                int labi = lab[i];
                float se = 0.0f, sp = 0.0f;
#pragma unroll
                for (int n = 0; n < 4; ++n) {
                    int j = jBase + wn * 64 + n * 16 + lrow;
                    float sim = acc[m][n][e] * INV_T;
                    if (j != i) {
                        se += __expf(sim);
                        if (labj[n] == labi) sp += sim;
                    }
                }
#pragma unroll
                for (int off = 8; off >= 1; off >>= 1) {
                    se += __shfl_xor(se, off, 16);
                    sp += __shfl_xor(sp, off, 16);
                }
                if (lrow == 0) {
                    atomicAdd(&ldsF[r], se);        // ds_add_f32: fold wn pair
                    atomicAdd(&ldsF[128 + r], sp);
                }
            }
        }
    } else {
        float sec[4] = {0, 0, 0, 0}, spc[4] = {0, 0, 0, 0};
#pragma unroll
        for (int m = 0; m < 4; ++m) {
#pragma unroll
            for (int e = 0; e < 4; ++e) {
                int r = wm * 64 + m * 16 + quad * 4 + e;
                int labi = lab[iBase + r];
                float se = 0.0f, sp = 0.0f;
#pragma unroll
                for (int n = 0; n < 4; ++n) {
                    float sim = acc[m][n][e] * INV_T;
                    float ex = __expf(sim);
                    se += ex;
                    sec[n] += ex;
                    if (labj[n] == labi) {
                        sp += sim;
                        spc[n] += sim;
                    }
                }
#pragma unroll
                for (int off = 8; off >= 1; off >>= 1) {
                    se += __shfl_xor(se, off, 16);
                    sp += __shfl_xor(sp, off, 16);
                }
                if (lrow == 0) {
                    atomicAdd(&ldsF[r], se);
                    atomicAdd(&ldsF[128 + r], sp);
                }
            }
        }
        // col partials: each lane holds 16-row partials; 4 quads + 2 wm waves
        // fold through LDS atomics (4-8 way, intra-CU).
#pragma unroll
        for (int n = 0; n < 4; ++n) {
            int c = wn * 64 + n * 16 + lrow;
            atomicAdd(&ldsF[256 + c], sec[n]);
            atomicAdd(&ldsF[384 + c], spc[n]);
        }
    }
    __syncthreads();

    // Collision-free slot stores: rows -> slot bj, cols -> slot bi.
    if (t < 128) {
        PE[(size_t)bj * N_ROWS + iBase + t] = ldsF[t];
        PP[(size_t)bj * N_ROWS + iBase + t] = ldsF[128 + t];
    } else if (!diag) {
        int c = t - 128;
        PE[(size_t)bi * N_ROWS + jBase + c] = ldsF[256 + c];
        PP[(size_t)bi * N_ROWS + jBase + c] = ldsF[384 + c];
    }
}

// 32 blocks x 256 rows: sum 64 slots, per-row loss, atomicAdd mean into out.
__global__ __launch_bounds__(256) void final_kernel(const float* __restrict__ PE,
                                                    const float* __restrict__ PP,
                                                    const int* __restrict__ lab,
                                                    const int* __restrict__ cnt,
                                                    float* __restrict__ out) {
    const int i = blockIdx.x * 256 + threadIdx.x;
    float se = 0.0f, sp = 0.0f;
#pragma unroll 8
    for (int s = 0; s < NSLOT; ++s) {
        se += PE[(size_t)s * N_ROWS + i];
        sp += PP[(size_t)s * N_ROWS + i];
    }
    const float c1 = (float)cnt[0];
    float np = (lab[i] ? c1 : (float)N_ROWS - c1) - 1.0f;
    float local = (np * __logf(se) - sp) / (np + 1e-8f);
    __shared__ float sh[4];
    int lane = threadIdx.x & 63, w = threadIdx.x >> 6;
#pragma unroll
    for (int off = 32; off >= 1; off >>= 1) local += __shfl_xor(local, off, 64);
    if (lane == 0) sh[w] = local;
    __syncthreads();
    if (threadIdx.x == 0)
        atomicAdd(out, (sh[0] + sh[1] + sh[2] + sh[3]) * (1.0f / (float)N_ROWS));
}

extern "C" void kernel_launch(void* const* d_in, const int* in_sizes, int n_in,
                              void* d_out, int out_size, void* d_ws, size_t ws_size,
                              hipStream_t stream) {
    const float* features = (const float*)d_in[0];
    const int* labels = (const int*)d_in[1];
    float* out = (float*)d_out;

    char* ws = (char*)d_ws;
    bf16_t* fbf = (bf16_t*)ws;                                    // 8 MiB
    float* PE = (float*)(ws + (size_t)N_ROWS * DIM * 2);          // 2 MiB
    float* PP = PE + (size_t)NSLOT * N_ROWS;                      // 2 MiB
    int* cnt = (int*)(PP + (size_t)NSLOT * N_ROWS);               // 4 B

    norm_kernel<<<N_ROWS / 4, 256, 0, stream>>>(features, fbf, labels, cnt, out);
    sim_kernel<<<NB * (NB + 1) / 2, 256, 0, stream>>>(fbf, labels, PE, PP);
    final_kernel<<<N_ROWS / 256, 256, 0, stream>>>(PE, PP, labels, cnt, out);
}